// Round 1
// baseline (721.129 us; speedup 1.0000x reference)
//
#include <hip/hip_runtime.h>
#include <math.h>

// Problem constants
#define F_DIM 64
#define N_NODES 64
#define T_LEN 24
#define N_HEADS 8
#define BATCH 16
#define E_DIM 4096          // F_DIM * N_NODES
#define HD 512              // E / N_HEADS
#define QKV_N 12288         // 3*E
#define MB 384              // T_LEN * BATCH
#define TS 23               // T_LEN - 1
#define MP 368              // TS * BATCH
#define MPAD 384            // padded row count for both GEMMs

typedef unsigned short ushort_t;
typedef short bf16x8 __attribute__((ext_vector_type(8)));
typedef float f32x4 __attribute__((ext_vector_type(4)));

// fp32 -> bf16, round-half-up (add 0x8000, truncate)
__device__ inline ushort_t f2bf(float f) {
    return (ushort_t)((__float_as_uint(f) + 0x8000u) >> 16);
}

// pack 8 fp32 -> 8 bf16 (round-half-up) via v_perm
__device__ inline bf16x8 cvt_bf8(const float4 lo, const float4 hi) {
    unsigned a0 = __float_as_uint(lo.x) + 0x8000u;
    unsigned a1 = __float_as_uint(lo.y) + 0x8000u;
    unsigned a2 = __float_as_uint(lo.z) + 0x8000u;
    unsigned a3 = __float_as_uint(lo.w) + 0x8000u;
    unsigned a4 = __float_as_uint(hi.x) + 0x8000u;
    unsigned a5 = __float_as_uint(hi.y) + 0x8000u;
    unsigned a6 = __float_as_uint(hi.z) + 0x8000u;
    unsigned a7 = __float_as_uint(hi.w) + 0x8000u;
    union { uint4 u; bf16x8 v; } r;
    r.u.x = __builtin_amdgcn_perm(a1, a0, 0x07060302u);
    r.u.y = __builtin_amdgcn_perm(a3, a2, 0x07060302u);
    r.u.z = __builtin_amdgcn_perm(a5, a4, 0x07060302u);
    r.u.w = __builtin_amdgcn_perm(a7, a6, 0x07060302u);
    return r.v;
}

// ---------------------------------------------------------------------------
// Kernel 0: xt[t*16+b, f*64+n] = bf16(x[b, f, t, n])
// ---------------------------------------------------------------------------
__global__ void k_transpose(const float* __restrict__ x, ushort_t* __restrict__ xt) {
    int m = blockIdx.x;              // t*16 + b
    int t = m >> 4, b = m & 15;
    const float* xb = x + (size_t)b * (F_DIM * T_LEN * N_NODES) + (size_t)t * N_NODES;
    ushort_t* row = xt + (size_t)m * E_DIM;
    for (int e = threadIdx.x; e < E_DIM; e += 256) {
        int f = e >> 6, n = e & 63;
        row[e] = f2bf(xb[(size_t)f * (T_LEN * N_NODES) + n]);
    }
}

// ---------------------------------------------------------------------------
// MFMA GEMM v2: barrier-free, LDS-free, per-wave register pipeline.
//   Block tile = 192 rows (M-split of 2) x 64 cols. 4 waves, each owns
//   48 rows x 64 cols = 3x4 16x16x32 frags (48 accum VGPRs/lane).
//   A (bf16, L2/L3-resident) loaded directly to frag regs.
//   B (fp32 weights) loaded per-wave, converted in-register via v_perm.
//   2-deep hand-unrolled pipeline: loads for k+32 issued before MFMA at k.
//   No __syncthreads in the K-loop -> no vmcnt(0) barrier drains; latency
//   hidden by TLP (grid = 2*NT*S blocks = 2-3 blocks/CU).
//   XCD pairing: blockIdx bits arranged so the two M-halves sharing a B
//   panel land 8 apart (same XCD under round-robin) -> B re-read hits L2.
//   Requires kc % 64 == 0 and kc >= 64.
// ---------------------------------------------------------------------------
__global__ __launch_bounds__(256) void k_gemm_mfma(
    const ushort_t* __restrict__ A, const float* __restrict__ B,
    float* __restrict__ P, int N, int K, int kc)
{
    const int tid  = threadIdx.x;
    const int wave = tid >> 6, lane = tid & 63;
    const int lr = lane & 15, lq = lane >> 4;

    // decode with XCD pairing: bx = ((ntile/8)*2 + mhalf)*8 + (ntile%8)
    const int bx = blockIdx.x;
    const int xcd = bx & 7, grp = bx >> 3;
    const int mhalf = grp & 1;
    const int ntile = (grp >> 1) * 8 + xcd;
    const int n0 = ntile * 64;
    const int m0 = mhalf * 192;
    const int kz = blockIdx.z * kc;

    const ushort_t* Ap = A + (size_t)(m0 + wave * 48 + lr) * K + kz + lq * 8;
    const float*    Bp = B + (size_t)(n0 + lr) * K + kz + lq * 8;
    const size_t RS16 = (size_t)16 * K;          // 16-row stride (elements)

    f32x4 acc[3][4];
    #pragma unroll
    for (int i = 0; i < 3; ++i)
        #pragma unroll
        for (int j = 0; j < 4; ++j)
            acc[i][j] = (f32x4){0.f, 0.f, 0.f, 0.f};

    bf16x8 a0[3], a1[3];
    float4 b0[4][2], b1[4][2];

    auto LDA = [&](bf16x8 (&dst)[3], int off) {
        #pragma unroll
        for (int i = 0; i < 3; ++i)
            dst[i] = *(const bf16x8*)(Ap + (size_t)i * RS16 + off);
    };
    auto LDB = [&](float4 (&dst)[4][2], int off) {
        #pragma unroll
        for (int j = 0; j < 4; ++j) {
            dst[j][0] = *(const float4*)(Bp + (size_t)j * RS16 + off);
            dst[j][1] = *(const float4*)(Bp + (size_t)j * RS16 + off + 4);
        }
    };
    auto MM = [&](bf16x8 (&af)[3], float4 (&bs)[4][2]) {
        bf16x8 bf[4];
        #pragma unroll
        for (int j = 0; j < 4; ++j) bf[j] = cvt_bf8(bs[j][0], bs[j][1]);
        #pragma unroll
        for (int i = 0; i < 3; ++i)
            #pragma unroll
            for (int j = 0; j < 4; ++j)
                acc[i][j] = __builtin_amdgcn_mfma_f32_16x16x32_bf16(af[i], bf[j], acc[i][j], 0, 0, 0);
    };

    LDA(a0, 0); LDB(b0, 0);
    int k = 0;
    for (; k + 64 < kc; k += 64) {
        LDA(a1, k + 32); LDB(b1, k + 32);   // prefetch next step
        MM(a0, b0);                          // compute k
        LDA(a0, k + 64); LDB(b0, k + 64);   // prefetch step after
        MM(a1, b1);                          // compute k+32
    }
    // tail pair (k == kc-64)
    LDA(a1, k + 32); LDB(b1, k + 32);
    MM(a0, b0);
    MM(a1, b1);

    // epilogue: raw partial store (all rows valid; no guards)
    float* Pz = P + (size_t)blockIdx.z * MPAD * N;
    #pragma unroll
    for (int i = 0; i < 3; ++i) {
        int m = m0 + wave * 48 + i * 16 + lq * 4;
        #pragma unroll
        for (int r = 0; r < 4; ++r) {
            #pragma unroll
            for (int j = 0; j < 4; ++j)
                Pz[(size_t)(m + r) * N + n0 + j * 16 + lr] = acc[i][j][r];
        }
    }
}

// ---------------------------------------------------------------------------
// k_reduce: C[m,n] = sum_s P[s,m,n] + bias[n]   (float4-vectorized)
// ---------------------------------------------------------------------------
__global__ void k_reduce(const float* __restrict__ P, const float* __restrict__ bias,
                         float* __restrict__ C, int N, int S) {
    int idx = blockIdx.x * 256 + threadIdx.x;      // float4 index; grid exact
    size_t e = (size_t)idx * 4;
    int n = (int)(e % N);
    float4 a = *(const float4*)(P + e);
    for (int s = 1; s < S; ++s) {
        const float4 b = *(const float4*)(P + (size_t)s * MPAD * N + e);
        a.x += b.x; a.y += b.y; a.z += b.z; a.w += b.w;
    }
    const float4 bb = *(const float4*)(bias + n);
    a.x += bb.x; a.y += bb.y; a.z += bb.z; a.w += bb.w;
    *(float4*)(C + e) = a;
}

// ---------------------------------------------------------------------------
// k_attn (fused scores + cbar): per (b,h):
//   scores -> prefix softmax -> wbar[t,k] = (1/(t+1)) sum_{q<=t} E[q,k]/S[q,t]
//   cbar[t*16+b, h*512+d] = bf16( sum_k wbar[t,k] * v[k,b,h,d] )
// ---------------------------------------------------------------------------
__global__ __launch_bounds__(512) void k_attn(const float* __restrict__ qkv,
                                              ushort_t* __restrict__ cbar) {
    int bh = blockIdx.x;             // b*8 + h
    int b = bh >> 3, h = bh & 7;
    __shared__ float vs[T_LEN * HD];     // 48 KB
    __shared__ float ss[T_LEN][25];
    __shared__ float isv[T_LEN][25];
    __shared__ float wbs[TS * T_LEN];
    int tid = threadIdx.x, wave = tid >> 6, lane = tid & 63;
    // V -> LDS (overlaps with score dots below)
    for (int i4 = tid; i4 < T_LEN * HD / 4; i4 += 512) {
        int t = i4 >> 7, d4 = (i4 & 127) * 4;
        *(float4*)&vs[t * HD + d4] =
            *(const float4*)&qkv[(size_t)(t * BATCH + b) * QKV_N + 2 * E_DIM + h * HD + d4];
    }
    const float scale = 0.044194173824159216f;   // 1/sqrt(512)
    for (int p = wave; p < T_LEN * T_LEN; p += 8) {   // wave-per-dot, coalesced
        int qi = p / 24, ki = p - qi * 24;
        const float* qp = qkv + (size_t)(qi * BATCH + b) * QKV_N + h * HD + lane * 8;
        const float* kp = qkv + (size_t)(ki * BATCH + b) * QKV_N + E_DIM + h * HD + lane * 8;
        float4 a0 = *(const float4*)qp, a1 = *(const float4*)(qp + 4);
        float4 c0 = *(const float4*)kp, c1 = *(const float4*)(kp + 4);
        float s = a0.x * c0.x + a0.y * c0.y + a0.z * c0.z + a0.w * c0.w
                + a1.x * c1.x + a1.y * c1.y + a1.z * c1.z + a1.w * c1.w;
        #pragma unroll
        for (int off = 32; off > 0; off >>= 1) s += __shfl_xor(s, off);
        if (lane == 0) {
            s *= scale;
            if (ki <= qi) s += 1.f;      // tril_add (includes diagonal)
            ss[qi][ki] = s;
        }
    }
    __syncthreads();
    if (tid < T_LEN) {
        int q = tid;
        float M = -1e30f;
        for (int k = 0; k < T_LEN; ++k) M = fmaxf(M, ss[q][k]);
        float run = 0.f;
        for (int k = 0; k < T_LEN; ++k) {
            float e = __expf(ss[q][k] - M);
            ss[q][k] = e;
            run += e;
            isv[q][k] = 1.f / run;   // 1 / S[q, t=k]
        }
    }
    __syncthreads();
    for (int p = tid; p < TS * T_LEN; p += 512) {
        int t = p / 24, k = p - t * 24;
        float w = 0.f;
        if (k <= t) {
            float sum = 0.f;
            for (int q = 0; q <= t; ++q) sum += ss[q][k] * isv[q][t];
            w = sum / (float)(t + 1);
        }
        wbs[p] = w;
    }
    __syncthreads();
    int d = tid;                        // 512 threads == HD
    for (int t = 0; t < TS; ++t) {
        float a = 0.f;
        #pragma unroll
        for (int k = 0; k < T_LEN; ++k) a += wbs[t * 24 + k] * vs[k * HD + d];
        cbar[(size_t)(t * BATCH + b) * E_DIM + h * HD + d] = f2bf(a);
    }
}

// ---------------------------------------------------------------------------
// k_final: out[b, f, t+1, n] = relu( sum_g pooled[t*16+b, f*64+g]*Wfc[n,g] + bfc[n] )
// ---------------------------------------------------------------------------
__global__ void k_final(const float* __restrict__ pooled, const float* __restrict__ Wfc,
                        const float* __restrict__ bfc, float* __restrict__ out) {
    int tb = blockIdx.x;             // t*16 + b
    int t = tb >> 4, b = tb & 15;
    __shared__ float ps[E_DIM];      // 16 KB
    __shared__ float wf[64 * 65];    // padded
    __shared__ float bf[64];
    int tid = threadIdx.x;
    for (int i = tid; i < E_DIM; i += 256) ps[i] = pooled[(size_t)tb * E_DIM + i];
    for (int i = tid; i < 64 * 64; i += 256) wf[(i >> 6) * 65 + (i & 63)] = Wfc[i];
    if (tid < 64) bf[tid] = bfc[tid];
    __syncthreads();
    for (int p = tid; p < 4096; p += 256) {
        int f = p >> 6, n = p & 63;
        float acc = bf[n];
        #pragma unroll
        for (int g = 0; g < 64; ++g) acc += ps[f * 64 + g] * wf[n * 65 + g];
        out[(size_t)((b * 64 + f) * T_LEN + (t + 1)) * N_NODES + n] = fmaxf(acc, 0.f);
    }
}

// k_first: out[b,f,0,n] = x[b,f,0,n]   (65536 elems, 256 blocks)
__global__ void k_first(const float* __restrict__ x, float* __restrict__ out) {
    int idx = blockIdx.x * 256 + threadIdx.x;
    if (idx >= BATCH * F_DIM * N_NODES) return;
    int b = idx >> 12, f = (idx >> 6) & 63, n = idx & 63;
    size_t o = ((size_t)(b * 64 + f) * T_LEN) * 64 + n;
    out[o] = x[o];
}

extern "C" void kernel_launch(void* const* d_in, const int* in_sizes, int n_in,
                              void* d_out, int out_size, void* d_ws, size_t ws_size,
                              hipStream_t stream) {
    const float* x    = (const float*)d_in[0];
    const float* Wqkv = (const float*)d_in[1];
    const float* bqkv = (const float*)d_in[2];
    const float* Wo   = (const float*)d_in[3];
    const float* bo   = (const float*)d_in[4];
    const float* Wfc  = (const float*)d_in[5];
    const float* bfc  = (const float*)d_in[6];
    float* out = (float*)d_out;

    // ws layout (bytes): xt bf16 | qkv f32 | cbar bf16 | pooled f32 | pbuf f32
    char* wsb = (char*)d_ws;
    ushort_t* xt   = (ushort_t*)wsb;                                  //  3,145,728
    float*    qkv  = (float*)(wsb + 3145728);                         // 18,874,368
    ushort_t* cbar = (ushort_t*)(wsb + 3145728 + 18874368);           //  3,145,728
    float*  pooled = (float*)(wsb + 3145728 + 18874368 + 3145728);    //  6,291,456
    size_t base    = 3145728 + 18874368 + 3145728 + 6291456;
    float*  pbuf   = (float*)(wsb + base);

    const size_t pq = (size_t)MPAD * QKV_N * 4;    // QKV partial: 18.87 MB
    const size_t po = (size_t)MPAD * E_DIM * 4;    // Wo partial:   6.29 MB
    int S   = (ws_size >= base + 2 * pq) ? 2 : 1;                // QKV K-split
    int Swo = (ws_size >= base + 4 * po) ? 4 : 1;                // Wo  K-split

    hipLaunchKernelGGL(k_transpose, dim3(MB), dim3(256), 0, stream, x, xt);

    // grid.x = 2 * (N/64): M-split of 2, XCD-paired decode in-kernel
    hipLaunchKernelGGL(k_gemm_mfma, dim3(2 * QKV_N / 64, 1, S), dim3(256), 0, stream,
                       xt, Wqkv, pbuf, QKV_N, E_DIM, E_DIM / S);
    hipLaunchKernelGGL(k_reduce, dim3(MPAD * QKV_N / 4 / 256), dim3(256), 0, stream,
                       pbuf, bqkv, qkv, QKV_N, S);

    hipLaunchKernelGGL(k_attn, dim3(BATCH * N_HEADS), dim3(512), 0, stream, qkv, cbar);

    hipLaunchKernelGGL(k_gemm_mfma, dim3(2 * E_DIM / 64, 1, Swo), dim3(256), 0, stream,
                       cbar, Wo, pbuf, E_DIM, E_DIM, E_DIM / Swo);
    hipLaunchKernelGGL(k_reduce, dim3(MPAD * E_DIM / 4 / 256), dim3(256), 0, stream,
                       pbuf, bo, pooled, E_DIM, Swo);

    hipLaunchKernelGGL(k_final, dim3(TS * BATCH), dim3(256), 0, stream, pooled, Wfc, bfc, out);
    hipLaunchKernelGGL(k_first, dim3((BATCH * F_DIM * N_NODES + 255) / 256), dim3(256), 0, stream, x, out);
}

// Round 3
// 545.918 us; speedup vs baseline: 1.3209x; 1.3209x over previous
//
#include <hip/hip_runtime.h>
#include <math.h>

// Problem constants
#define F_DIM 64
#define N_NODES 64
#define T_LEN 24
#define N_HEADS 8
#define BATCH 16
#define E_DIM 4096          // F_DIM * N_NODES
#define HD 512              // E / N_HEADS
#define QKV_N 12288         // 3*E
#define MB 384              // T_LEN * BATCH
#define TS 23               // T_LEN - 1
#define MP 368              // TS * BATCH
#define MPAD 384            // padded row count for both GEMMs

typedef unsigned short ushort_t;
typedef short bf16x8 __attribute__((ext_vector_type(8)));
typedef float f32x4 __attribute__((ext_vector_type(4)));

// fp32 -> bf16, round-half-up (add 0x8000, truncate)
__device__ inline ushort_t f2bf(float f) {
    return (ushort_t)((__float_as_uint(f) + 0x8000u) >> 16);
}

// async global->LDS, 16B per lane. LDS dest = uniform base + lane*16.
__device__ inline void async_load16(const ushort_t* g, ushort_t* lds) {
    __builtin_amdgcn_global_load_lds(
        (const __attribute__((address_space(1))) unsigned int*)g,
        (__attribute__((address_space(3))) unsigned int*)lds,
        16, 0, 0);
}

// ---------------------------------------------------------------------------
// Kernel 0: xt[t*16+b, f*64+n] = bf16(x[b, f, t, n])
// ---------------------------------------------------------------------------
__global__ void k_transpose(const float* __restrict__ x, ushort_t* __restrict__ xt) {
    int m = blockIdx.x;              // t*16 + b
    int t = m >> 4, b = m & 15;
    const float* xb = x + (size_t)b * (F_DIM * T_LEN * N_NODES) + (size_t)t * N_NODES;
    ushort_t* row = xt + (size_t)m * E_DIM;
    for (int e = threadIdx.x; e < E_DIM; e += 256) {
        int f = e >> 6, n = e & 63;
        row[e] = f2bf(xb[(size_t)f * (T_LEN * N_NODES) + n]);
    }
}

// ---------------------------------------------------------------------------
// MFMA GEMM v3: M-full tile 384 x 64, BK=32, deep-pipelined LDS staging.
//  - A (bf16): global_load_lds into 3 rotating LDS buffers, issued 2 K-steps
//    ahead; s_waitcnt vmcnt(8) (counted, never 0 mid-loop) + raw s_barrier.
//  - B (fp32 weights): reg-staged 2 steps ahead (2 float4/thread), converted
//    to bf16 via v_perm, ds_written just before the barrier (T14 split).
//  - LDS XOR swizzle (16B slot ^= (row>>1)&3) on both A (pre-swizzled global
//    source, linear glds dest) and B (swizzled ds_write + ds_read) kills the
//    8-way ds_read_b128 bank conflict of the naive [row][32] layout.
//  - 4 waves; wave owns 96 rows x 64 cols = 6x4 16x16x32 frags.
//  - K-split via blockIdx.z (kc cols each); raw partials, reduced later.
//  Requires kc % 64 == 0 (nt even, >= 2).
// ---------------------------------------------------------------------------
__global__ __launch_bounds__(256, 2) void k_gemm_mfma(
    const ushort_t* __restrict__ A, const float* __restrict__ B,
    float* __restrict__ P, int N, int K, int kc)
{
    __shared__ __align__(16) ushort_t As[3][384 * 32];   // 3 x 24 KB
    __shared__ __align__(16) ushort_t Bs[2][64 * 32];    // 2 x 4 KB
    const int tid  = threadIdx.x;
    const int wave = tid >> 6, lane = tid & 63;
    const int lr = lane & 15, lq = lane >> 4;
    const int n0 = blockIdx.x * 64;
    const int kz = blockIdx.z * kc;
    const int nt = kc / 32;                       // even, >= 2

    // ---- A glds setup: 6 instrs/wave; source pre-swizzled so that linear
    //      LDS slot (lane&3) receives k-chunk (lane&3)^((lane>>3)&3). ----
    const int rb = lane >> 2;
    const int cc = ((lane & 3) ^ ((lane >> 3) & 3)) * 8;   // k-elems
    const ushort_t* gA[6];
    int lA[6];
    #pragma unroll
    for (int s = 0; s < 6; ++s) {
        int r = (wave * 6 + s) * 16 + rb;
        gA[s] = A + (size_t)r * K + kz + cc;
        lA[s] = (wave * 6 + s) * 512;             // ushort offset of instr base
    }

    // ---- B reg-stage setup: 2 float4/thread; swizzled LDS write offsets ----
    const int e40 = tid, e41 = tid + 256;
    const int r0 = e40 >> 3, q0 = e40 & 7;
    const int r1 = e41 >> 3, q1 = e41 & 7;
    const float* gB0 = B + (size_t)(n0 + r0) * K + kz + q0 * 4;
    const float* gB1 = B + (size_t)(n0 + r1) * K + kz + q1 * 4;
    const int wb0 = r0 * 64 + (((q0 >> 1) ^ ((r0 >> 1) & 3)) << 4) + ((q0 & 1) << 3);
    const int wb1 = r1 * 64 + (((q1 >> 1) ^ ((r1 >> 1) & 3)) << 4) + ((q1 & 1) << 3);

    // ---- swizzled per-lane read offsets ----
    const int sw   = ((lq ^ ((lr >> 1) & 3)) << 4);
    const int aoff = (wave * 96 + lr) * 64 + sw;  // + i*1024 per 16-row frag
    const int boff = lr * 64 + sw;                // + j*1024 per 16-row frag

    f32x4 acc[6][4];
    #pragma unroll
    for (int i = 0; i < 6; ++i)
        #pragma unroll
        for (int j = 0; j < 4; ++j)
            acc[i][j] = (f32x4){0.f, 0.f, 0.f, 0.f};

    ushort_t* paR = &As[0][0];    // buffer for step t
    ushort_t* paN = &As[1][0];    // buffer for step t+1
    ushort_t* paW = &As[2][0];    // glds target for step t+2

    float4 bA0, bA1, bB0, bB1;

    // prologue: issue t=0 and t=1 (8 vmem ops each: 6 glds + 2 B loads)
    #pragma unroll
    for (int s = 0; s < 6; ++s) async_load16(gA[s], paR + lA[s]);
    bA0 = *(const float4*)gB0;
    bA1 = *(const float4*)gB1;
    #pragma unroll
    for (int s = 0; s < 6; ++s) async_load16(gA[s] + 32, paN + lA[s]);
    bB0 = *(const float4*)(gB0 + 32);
    bB1 = *(const float4*)(gB1 + 32);

    auto conv8 = [](const float4 v) -> uint2 {
        unsigned x = __float_as_uint(v.x) + 0x8000u;
        unsigned y = __float_as_uint(v.y) + 0x8000u;
        unsigned z = __float_as_uint(v.z) + 0x8000u;
        unsigned w = __float_as_uint(v.w) + 0x8000u;
        return make_uint2(__builtin_amdgcn_perm(y, x, 0x07060302u),
                          __builtin_amdgcn_perm(w, z, 0x07060302u));
    };

    auto compute = [&](const ushort_t* pa, const ushort_t* bsb) {
        bf16x8 bfr[4];
        #pragma unroll
        for (int j = 0; j < 4; ++j)
            bfr[j] = *(const bf16x8*)((const char*)bsb + j * 1024 + boff);
        #pragma unroll
        for (int i = 0; i < 6; ++i) {
            bf16x8 af = *(const bf16x8*)((const char*)pa + i * 1024 + aoff);
            #pragma unroll
            for (int j = 0; j < 4; ++j)
                acc[i][j] = __builtin_amdgcn_mfma_f32_16x16x32_bf16(af, bfr[j], acc[i][j], 0, 0, 0);
        }
    };

    for (int tt = 0; tt < nt; tt += 2) {
        // ======== sub-step t = tt (even): Bs[0], bA ========
        // wait: loads for t done; t+1's 8 stay in flight across the barrier
        asm volatile("s_waitcnt vmcnt(8)" ::: "memory");
        *(uint2*)((char*)&Bs[0][0] + wb0) = conv8(bA0);
        *(uint2*)((char*)&Bs[0][0] + wb1) = conv8(bA1);
        asm volatile("s_waitcnt lgkmcnt(0)" ::: "memory");
        __builtin_amdgcn_s_barrier();
        __builtin_amdgcn_sched_barrier(0);
        if (tt + 2 < nt) {                      // issue t+2 into paW
            const int ko = (tt + 2) * 32;
            #pragma unroll
            for (int s = 0; s < 6; ++s) async_load16(gA[s] + ko, paW + lA[s]);
            bA0 = *(const float4*)(gB0 + ko);
            bA1 = *(const float4*)(gB1 + ko);
        }
        compute(paR, &Bs[0][0]);
        { ushort_t* tmp = paR; paR = paN; paN = paW; paW = tmp; }

        // ======== sub-step t = tt+1 (odd): Bs[1], bB ========
        if (tt + 1 < nt - 1) { asm volatile("s_waitcnt vmcnt(8)" ::: "memory"); }
        else                 { asm volatile("s_waitcnt vmcnt(0)" ::: "memory"); }
        *(uint2*)((char*)&Bs[1][0] + wb0) = conv8(bB0);
        *(uint2*)((char*)&Bs[1][0] + wb1) = conv8(bB1);
        asm volatile("s_waitcnt lgkmcnt(0)" ::: "memory");
        __builtin_amdgcn_s_barrier();
        __builtin_amdgcn_sched_barrier(0);
        if (tt + 3 < nt) {                      // issue t+3 into paW
            const int ko = (tt + 3) * 32;
            #pragma unroll
            for (int s = 0; s < 6; ++s) async_load16(gA[s] + ko, paW + lA[s]);
            bB0 = *(const float4*)(gB0 + ko);
            bB1 = *(const float4*)(gB1 + ko);
        }
        compute(paR, &Bs[1][0]);
        { ushort_t* tmp = paR; paR = paN; paN = paW; paW = tmp; }
    }

    // epilogue: raw partial store (all 384 rows valid; no guards)
    float* Pz = P + (size_t)blockIdx.z * MPAD * N;
    #pragma unroll
    for (int i = 0; i < 6; ++i) {
        int m = wave * 96 + i * 16 + lq * 4;
        #pragma unroll
        for (int r = 0; r < 4; ++r) {
            #pragma unroll
            for (int j = 0; j < 4; ++j)
                Pz[(size_t)(m + r) * N + n0 + j * 16 + lr] = acc[i][j][r];
        }
    }
}

// ---------------------------------------------------------------------------
// k_reduce: C[m,n] = sum_s P[s,m,n] + bias[n]   (float4-vectorized)
// ---------------------------------------------------------------------------
__global__ void k_reduce(const float* __restrict__ P, const float* __restrict__ bias,
                         float* __restrict__ C, int N, int S) {
    int idx = blockIdx.x * 256 + threadIdx.x;      // float4 index; grid exact
    size_t e = (size_t)idx * 4;
    int n = (int)(e % N);
    float4 a = *(const float4*)(P + e);
    for (int s = 1; s < S; ++s) {
        const float4 b = *(const float4*)(P + (size_t)s * MPAD * N + e);
        a.x += b.x; a.y += b.y; a.z += b.z; a.w += b.w;
    }
    const float4 bb = *(const float4*)(bias + n);
    a.x += bb.x; a.y += bb.y; a.z += bb.z; a.w += bb.w;
    *(float4*)(C + e) = a;
}

// ---------------------------------------------------------------------------
// k_attn (fused scores + cbar): per (b,h):
//   scores -> prefix softmax -> wbar[t,k] = (1/(t+1)) sum_{q<=t} E[q,k]/S[q,t]
//   cbar[t*16+b, h*512+d] = bf16( sum_k wbar[t,k] * v[k,b,h,d] )
// ---------------------------------------------------------------------------
__global__ __launch_bounds__(512) void k_attn(const float* __restrict__ qkv,
                                              ushort_t* __restrict__ cbar) {
    int bh = blockIdx.x;             // b*8 + h
    int b = bh >> 3, h = bh & 7;
    __shared__ float vs[T_LEN * HD];     // 48 KB
    __shared__ float ss[T_LEN][25];
    __shared__ float isv[T_LEN][25];
    __shared__ float wbs[TS * T_LEN];
    int tid = threadIdx.x, wave = tid >> 6, lane = tid & 63;
    // V -> LDS (overlaps with score dots below)
    for (int i4 = tid; i4 < T_LEN * HD / 4; i4 += 512) {
        int t = i4 >> 7, d4 = (i4 & 127) * 4;
        *(float4*)&vs[t * HD + d4] =
            *(const float4*)&qkv[(size_t)(t * BATCH + b) * QKV_N + 2 * E_DIM + h * HD + d4];
    }
    const float scale = 0.044194173824159216f;   // 1/sqrt(512)
    for (int p = wave; p < T_LEN * T_LEN; p += 8) {   // wave-per-dot, coalesced
        int qi = p / 24, ki = p - qi * 24;
        const float* qp = qkv + (size_t)(qi * BATCH + b) * QKV_N + h * HD + lane * 8;
        const float* kp = qkv + (size_t)(ki * BATCH + b) * QKV_N + E_DIM + h * HD + lane * 8;
        float4 a0 = *(const float4*)qp, a1 = *(const float4*)(qp + 4);
        float4 c0 = *(const float4*)kp, c1 = *(const float4*)(kp + 4);
        float s = a0.x * c0.x + a0.y * c0.y + a0.z * c0.z + a0.w * c0.w
                + a1.x * c1.x + a1.y * c1.y + a1.z * c1.z + a1.w * c1.w;
        #pragma unroll
        for (int off = 32; off > 0; off >>= 1) s += __shfl_xor(s, off);
        if (lane == 0) {
            s *= scale;
            if (ki <= qi) s += 1.f;      // tril_add (includes diagonal)
            ss[qi][ki] = s;
        }
    }
    __syncthreads();
    if (tid < T_LEN) {
        int q = tid;
        float M = -1e30f;
        for (int k = 0; k < T_LEN; ++k) M = fmaxf(M, ss[q][k]);
        float run = 0.f;
        for (int k = 0; k < T_LEN; ++k) {
            float e = __expf(ss[q][k] - M);
            ss[q][k] = e;
            run += e;
            isv[q][k] = 1.f / run;   // 1 / S[q, t=k]
        }
    }
    __syncthreads();
    for (int p = tid; p < TS * T_LEN; p += 512) {
        int t = p / 24, k = p - t * 24;
        float w = 0.f;
        if (k <= t) {
            float sum = 0.f;
            for (int q = 0; q <= t; ++q) sum += ss[q][k] * isv[q][t];
            w = sum / (float)(t + 1);
        }
        wbs[p] = w;
    }
    __syncthreads();
    int d = tid;                        // 512 threads == HD
    for (int t = 0; t < TS; ++t) {
        float a = 0.f;
        #pragma unroll
        for (int k = 0; k < T_LEN; ++k) a += wbs[t * 24 + k] * vs[k * HD + d];
        cbar[(size_t)(t * BATCH + b) * E_DIM + h * HD + d] = f2bf(a);
    }
}

// ---------------------------------------------------------------------------
// k_final: out[b, f, t+1, n] = relu( sum_g pooled[t*16+b, f*64+g]*Wfc[n,g] + bfc[n] )
// ---------------------------------------------------------------------------
__global__ void k_final(const float* __restrict__ pooled, const float* __restrict__ Wfc,
                        const float* __restrict__ bfc, float* __restrict__ out) {
    int tb = blockIdx.x;             // t*16 + b
    int t = tb >> 4, b = tb & 15;
    __shared__ float ps[E_DIM];      // 16 KB
    __shared__ float wf[64 * 65];    // padded
    __shared__ float bf[64];
    int tid = threadIdx.x;
    for (int i = tid; i < E_DIM; i += 256) ps[i] = pooled[(size_t)tb * E_DIM + i];
    for (int i = tid; i < 64 * 64; i += 256) wf[(i >> 6) * 65 + (i & 63)] = Wfc[i];
    if (tid < 64) bf[tid] = bfc[tid];
    __syncthreads();
    for (int p = tid; p < 4096; p += 256) {
        int f = p >> 6, n = p & 63;
        float acc = bf[n];
        #pragma unroll
        for (int g = 0; g < 64; ++g) acc += ps[f * 64 + g] * wf[n * 65 + g];
        out[(size_t)((b * 64 + f) * T_LEN + (t + 1)) * N_NODES + n] = fmaxf(acc, 0.f);
    }
}

// k_first: out[b,f,0,n] = x[b,f,0,n]   (65536 elems, 256 blocks)
__global__ void k_first(const float* __restrict__ x, float* __restrict__ out) {
    int idx = blockIdx.x * 256 + threadIdx.x;
    if (idx >= BATCH * F_DIM * N_NODES) return;
    int b = idx >> 12, f = (idx >> 6) & 63, n = idx & 63;
    size_t o = ((size_t)(b * 64 + f) * T_LEN) * 64 + n;
    out[o] = x[o];
}

extern "C" void kernel_launch(void* const* d_in, const int* in_sizes, int n_in,
                              void* d_out, int out_size, void* d_ws, size_t ws_size,
                              hipStream_t stream) {
    const float* x    = (const float*)d_in[0];
    const float* Wqkv = (const float*)d_in[1];
    const float* bqkv = (const float*)d_in[2];
    const float* Wo   = (const float*)d_in[3];
    const float* bo   = (const float*)d_in[4];
    const float* Wfc  = (const float*)d_in[5];
    const float* bfc  = (const float*)d_in[6];
    float* out = (float*)d_out;

    // ws layout (bytes): xt bf16 | qkv f32 | cbar bf16 | pooled f32 | pbuf f32
    char* wsb = (char*)d_ws;
    ushort_t* xt   = (ushort_t*)wsb;                                  //  3,145,728
    float*    qkv  = (float*)(wsb + 3145728);                         // 18,874,368
    ushort_t* cbar = (ushort_t*)(wsb + 3145728 + 18874368);           //  3,145,728
    float*  pooled = (float*)(wsb + 3145728 + 18874368 + 3145728);    //  6,291,456
    size_t base    = 3145728 + 18874368 + 3145728 + 6291456;
    float*  pbuf   = (float*)(wsb + base);

    const size_t pq = (size_t)MPAD * QKV_N * 4;    // QKV partial: 18.87 MB
    const size_t po = (size_t)MPAD * E_DIM * 4;    // Wo partial:   6.29 MB
    // K-splits for occupancy (2 blocks/CU needs >=512 blocks); kc % 64 == 0
    int S   = (ws_size >= base + 4 * pq) ? 4 : ((ws_size >= base + 2 * pq) ? 2 : 1);
    int Swo = (ws_size >= base + 8 * po) ? 8 : ((ws_size >= base + 4 * po) ? 4 : 1);

    hipLaunchKernelGGL(k_transpose, dim3(MB), dim3(256), 0, stream, x, xt);

    hipLaunchKernelGGL(k_gemm_mfma, dim3(QKV_N / 64, 1, S), dim3(256), 0, stream,
                       xt, Wqkv, pbuf, QKV_N, E_DIM, E_DIM / S);
    hipLaunchKernelGGL(k_reduce, dim3(MPAD * QKV_N / 4 / 256), dim3(256), 0, stream,
                       pbuf, bqkv, qkv, QKV_N, S);

    hipLaunchKernelGGL(k_attn, dim3(BATCH * N_HEADS), dim3(512), 0, stream, qkv, cbar);

    hipLaunchKernelGGL(k_gemm_mfma, dim3(E_DIM / 64, 1, Swo), dim3(256), 0, stream,
                       cbar, Wo, pbuf, E_DIM, E_DIM, E_DIM / Swo);
    hipLaunchKernelGGL(k_reduce, dim3(MPAD * E_DIM / 4 / 256), dim3(256), 0, stream,
                       pbuf, bo, pooled, E_DIM, Swo);

    hipLaunchKernelGGL(k_final, dim3(TS * BATCH), dim3(256), 0, stream, pooled, Wfc, bfc, out);
    hipLaunchKernelGGL(k_first, dim3((BATCH * F_DIM * N_NODES + 255) / 256), dim3(256), 0, stream, x, out);
}

// Round 8
// 531.040 us; speedup vs baseline: 1.3580x; 1.0280x over previous
//
#include <hip/hip_runtime.h>
#include <math.h>

// Problem constants
#define F_DIM 64
#define N_NODES 64
#define T_LEN 24
#define N_HEADS 8
#define BATCH 16
#define E_DIM 4096          // F_DIM * N_NODES
#define HD 512              // E / N_HEADS
#define QKV_N 12288         // 3*E
#define MB 384              // T_LEN * BATCH
#define TS 23               // T_LEN - 1
#define MP 368              // TS * BATCH
#define MPAD 384            // padded row count for both GEMMs

typedef unsigned short ushort_t;
typedef short bf16x8 __attribute__((ext_vector_type(8)));
typedef float f32x4 __attribute__((ext_vector_type(4)));

// fp32 -> bf16, round-half-up (add 0x8000, truncate)
__device__ inline ushort_t f2bf(float f) {
    return (ushort_t)((__float_as_uint(f) + 0x8000u) >> 16);
}

// async global->LDS, 16B per lane. LDS dest = uniform base + lane*16.
__device__ inline void async_load16(const ushort_t* g, ushort_t* lds) {
    __builtin_amdgcn_global_load_lds(
        (const __attribute__((address_space(1))) unsigned int*)g,
        (__attribute__((address_space(3))) unsigned int*)lds,
        16, 0, 0);
}

__device__ inline uint2 conv8(const float4 v) {
    unsigned x = __float_as_uint(v.x) + 0x8000u;
    unsigned y = __float_as_uint(v.y) + 0x8000u;
    unsigned z = __float_as_uint(v.z) + 0x8000u;
    unsigned w = __float_as_uint(v.w) + 0x8000u;
    return make_uint2(__builtin_amdgcn_perm(y, x, 0x07060302u),
                      __builtin_amdgcn_perm(w, z, 0x07060302u));
}

// ---------------------------------------------------------------------------
// Kernel 0: xt[t*16+b, f*64+n] = bf16(x[b, f, t, n])
// ---------------------------------------------------------------------------
__global__ void k_transpose(const float* __restrict__ x, ushort_t* __restrict__ xt) {
    int m = blockIdx.x;              // t*16 + b
    int t = m >> 4, b = m & 15;
    const float* xb = x + (size_t)b * (F_DIM * T_LEN * N_NODES) + (size_t)t * N_NODES;
    ushort_t* row = xt + (size_t)m * E_DIM;
    for (int e = threadIdx.x; e < E_DIM; e += 256) {
        int f = e >> 6, n = e & 63;
        row[e] = f2bf(xb[(size_t)f * (T_LEN * N_NODES) + n]);
    }
}

// ---------------------------------------------------------------------------
// MFMA GEMM v4: M-full tile 384 x 64, BK=32, ds_read-FIRST pipelined staging.
//  Step t:  vmcnt(counted) -> ds_read frags -> lgkmcnt(0) -> issue prefetch
//           (6 glds A + batched B loads) -> s_barrier -> ds_write B(t+2)
//           -> MFMA (setprio).
//  ds_reads never follow a same-step glds in program order, so the compiler's
//  conservative LDS-DMA alias wait cannot drain the fresh prefetch (the R3
//  failure mode). A double-buffered in two SEPARATE __shared__ objects
//  (wave-exclusive rows -> vmcnt-only, no barrier publish needed).
//  B fp32 loaded 2 K-steps per batch (256 B/row-visit), converted via v_perm,
//  ds_written post-barrier into a 4-deep ring, read 2 steps later.
//  vmcnt: 6 (even steps), 10 (odd), 0 (last). One s_barrier per step.
//  Requires kc % 128 == 0 (nt % 4 == 0, nt >= 8).
// ---------------------------------------------------------------------------
__global__ __launch_bounds__(256, 2) void k_gemm_mfma(
    const ushort_t* __restrict__ A, const float* __restrict__ B,
    float* __restrict__ P, int N, int K, int kc)
{
    __shared__ __align__(16) ushort_t As0[384 * 32];   // 24 KB (even steps)
    __shared__ __align__(16) ushort_t As1[384 * 32];   // 24 KB (odd steps)
    __shared__ __align__(16) ushort_t Bs[4][64 * 32];  // 4 x 4 KB ring
    const int tid  = threadIdx.x;
    const int wave = tid >> 6, lane = tid & 63;
    const int lr = lane & 15, lq = lane >> 4;
    const int n0 = blockIdx.x * 64;
    const int kz = blockIdx.z * kc;
    const int nt = kc / 32;                       // multiple of 4, >= 8

    // ---- A glds setup: 6 instrs/wave; source pre-swizzled so that linear
    //      LDS slot (lane&3) receives k-chunk (lane&3)^((lane>>3)&3). ----
    const int rb = lane >> 2;
    const int cc = ((lane & 3) ^ ((lane >> 3) & 3)) * 8;   // k-elems
    const ushort_t* gA[6];
    int lA[6];
    #pragma unroll
    for (int s = 0; s < 6; ++s) {
        int r = (wave * 6 + s) * 16 + rb;
        gA[s] = A + (size_t)r * K + kz + cc;
        lA[s] = (wave * 6 + s) * 512;             // ushort offset of instr base
    }

    // ---- B reg-stage setup: 2 float4/thread/step; swizzled LDS write offs ----
    const int e40 = tid, e41 = tid + 256;
    const int r0 = e40 >> 3, q0 = e40 & 7;
    const int r1 = e41 >> 3, q1 = e41 & 7;
    const float* gB0 = B + (size_t)(n0 + r0) * K + kz + q0 * 4;
    const float* gB1 = B + (size_t)(n0 + r1) * K + kz + q1 * 4;
    const int wb0 = r0 * 64 + (((q0 >> 1) ^ ((r0 >> 1) & 3)) << 4) + ((q0 & 1) << 3);
    const int wb1 = r1 * 64 + (((q1 >> 1) ^ ((r1 >> 1) & 3)) << 4) + ((q1 & 1) << 3);

    // ---- swizzled per-lane read offsets (bytes) ----
    const int sw   = ((lq ^ ((lr >> 1) & 3)) << 4);
    const int aoff = (wave * 96 + lr) * 64 + sw;  // + i*1024 per 16-row frag
    const int boff = lr * 64 + sw;                // + j*1024 per 16-row frag

    f32x4 acc[6][4];
    #pragma unroll
    for (int i = 0; i < 6; ++i)
        #pragma unroll
        for (int j = 0; j < 4; ++j)
            acc[i][j] = (f32x4){0.f, 0.f, 0.f, 0.f};

    float4 bA0 = {0,0,0,0}, bA1 = {0,0,0,0};   // B data for even step t+2
    float4 bB0 = {0,0,0,0}, bB1 = {0,0,0,0};   // B data for odd  step t+3
    uint2 wE0, wE1, wO0, wO1;

    // ================= prologue =================
    // B data for steps 0..3 (direct), A for steps 0,1 (glds).
    float4 p00 = *(const float4*)(gB0);
    float4 p01 = *(const float4*)(gB1);
    float4 p10 = *(const float4*)(gB0 + 32);
    float4 p11 = *(const float4*)(gB1 + 32);
    float4 p20 = *(const float4*)(gB0 + 64);
    float4 p21 = *(const float4*)(gB1 + 64);
    float4 p30 = *(const float4*)(gB0 + 96);
    float4 p31 = *(const float4*)(gB1 + 96);
    __builtin_amdgcn_sched_barrier(0);
    #pragma unroll
    for (int s = 0; s < 6; ++s) async_load16(gA[s], As0 + lA[s]);
    #pragma unroll
    for (int s = 0; s < 6; ++s) async_load16(gA[s] + 32, As1 + lA[s]);
    __builtin_amdgcn_sched_barrier(0);
    asm volatile("s_waitcnt vmcnt(12)" ::: "memory");   // drain the 8 p-loads
    *(uint2*)((char*)&Bs[0][0] + wb0) = conv8(p00);
    *(uint2*)((char*)&Bs[0][0] + wb1) = conv8(p01);
    *(uint2*)((char*)&Bs[1][0] + wb0) = conv8(p10);
    *(uint2*)((char*)&Bs[1][0] + wb1) = conv8(p11);
    *(uint2*)((char*)&Bs[2][0] + wb0) = conv8(p20);
    *(uint2*)((char*)&Bs[2][0] + wb1) = conv8(p21);
    *(uint2*)((char*)&Bs[3][0] + wb0) = conv8(p30);
    *(uint2*)((char*)&Bs[3][0] + wb1) = conv8(p31);
    asm volatile("s_waitcnt lgkmcnt(0)" ::: "memory");
    __builtin_amdgcn_s_barrier();
    __builtin_amdgcn_sched_barrier(0);

    // ================= steady loop (4-step unrolled, static buffers) =========
    auto mfma_block = [&](bf16x8 (&af)[6], bf16x8 (&bfr)[4]) {
        __builtin_amdgcn_s_setprio(1);
        #pragma unroll
        for (int i = 0; i < 6; ++i)
            #pragma unroll
            for (int j = 0; j < 4; ++j)
                acc[i][j] = __builtin_amdgcn_mfma_f32_16x16x32_bf16(af[i], bfr[j], acc[i][j], 0, 0, 0);
        __builtin_amdgcn_s_setprio(0);
    };

    auto step_even = [&](int t, ushort_t* bsr, ushort_t* bsw) {
        // drains: G_A(t) [6] + G_B(t+2,t+3) [4] (issued at t-2); leaves G_A(t+1)
        asm volatile("s_waitcnt vmcnt(6)" ::: "memory");
        wE0 = conv8(bA0); wE1 = conv8(bA1);     // data t+2 (written this step)
        wO0 = conv8(bB0); wO1 = conv8(bB1);     // data t+3 (written next step)
        bf16x8 af[6], bfr[4];
        #pragma unroll
        for (int j = 0; j < 4; ++j)
            bfr[j] = *(const bf16x8*)((const char*)bsr + j * 1024 + boff);
        #pragma unroll
        for (int i = 0; i < 6; ++i)
            af[i] = *(const bf16x8*)((const char*)As0 + i * 1024 + aoff);
        asm volatile("s_waitcnt lgkmcnt(0)" ::: "memory");
        __builtin_amdgcn_sched_barrier(0);
        if (t + 2 < nt) {
            const int ko = (t + 2) * 32;
            #pragma unroll
            for (int s = 0; s < 6; ++s) async_load16(gA[s] + ko, As0 + lA[s]);
            const int k4 = (t + 4 < nt) ? (t + 4) * 32 : 0;   // dummy if past end
            const int k5 = (t + 5 < nt) ? (t + 5) * 32 : 0;
            bA0 = *(const float4*)(gB0 + k4); bA1 = *(const float4*)(gB1 + k4);
            bB0 = *(const float4*)(gB0 + k5); bB1 = *(const float4*)(gB1 + k5);
        }
        __builtin_amdgcn_s_barrier();
        __builtin_amdgcn_sched_barrier(0);
        if (t >= 2 && t + 2 < nt) {
            *(uint2*)((char*)bsw + wb0) = wE0;
            *(uint2*)((char*)bsw + wb1) = wE1;
        }
        mfma_block(af, bfr);
    };

    auto step_odd = [&](int t, ushort_t* bsr, ushort_t* bsw) {
        if (t == nt - 1) { asm volatile("s_waitcnt vmcnt(0)" ::: "memory"); }
        else             { asm volatile("s_waitcnt vmcnt(10)" ::: "memory"); }
        bf16x8 af[6], bfr[4];
        #pragma unroll
        for (int j = 0; j < 4; ++j)
            bfr[j] = *(const bf16x8*)((const char*)bsr + j * 1024 + boff);
        #pragma unroll
        for (int i = 0; i < 6; ++i)
            af[i] = *(const bf16x8*)((const char*)As1 + i * 1024 + aoff);
        asm volatile("s_waitcnt lgkmcnt(0)" ::: "memory");
        __builtin_amdgcn_sched_barrier(0);
        if (t + 2 < nt) {
            const int ko = (t + 2) * 32;
            #pragma unroll
            for (int s = 0; s < 6; ++s) async_load16(gA[s] + ko, As1 + lA[s]);
        }
        __builtin_amdgcn_s_barrier();
        __builtin_amdgcn_sched_barrier(0);
        if (t >= 3 && t + 2 < nt) {
            *(uint2*)((char*)bsw + wb0) = wO0;
            *(uint2*)((char*)bsw + wb1) = wO1;
        }
        mfma_block(af, bfr);
    };

    for (int tt = 0; tt < nt; tt += 4) {
        step_even(tt,     &Bs[0][0], &Bs[2][0]);
        step_odd (tt + 1, &Bs[1][0], &Bs[3][0]);
        step_even(tt + 2, &Bs[2][0], &Bs[0][0]);
        step_odd (tt + 3, &Bs[3][0], &Bs[1][0]);
    }

    // epilogue: raw partial store (all 384 rows valid; no guards)
    float* Pz = P + (size_t)blockIdx.z * MPAD * N;
    #pragma unroll
    for (int i = 0; i < 6; ++i) {
        int m = wave * 96 + i * 16 + lq * 4;
        #pragma unroll
        for (int r = 0; r < 4; ++r) {
            #pragma unroll
            for (int j = 0; j < 4; ++j)
                Pz[(size_t)(m + r) * N + n0 + j * 16 + lr] = acc[i][j][r];
        }
    }
}

// ---------------------------------------------------------------------------
// k_reduce: C[m,n] = sum_s P[s,m,n] + bias[n]   (float4-vectorized)
// ---------------------------------------------------------------------------
__global__ void k_reduce(const float* __restrict__ P, const float* __restrict__ bias,
                         float* __restrict__ C, int N, int S) {
    int idx = blockIdx.x * 256 + threadIdx.x;      // float4 index; grid exact
    size_t e = (size_t)idx * 4;
    int n = (int)(e % N);
    float4 a = *(const float4*)(P + e);
    for (int s = 1; s < S; ++s) {
        const float4 b = *(const float4*)(P + (size_t)s * MPAD * N + e);
        a.x += b.x; a.y += b.y; a.z += b.z; a.w += b.w;
    }
    const float4 bb = *(const float4*)(bias + n);
    a.x += bb.x; a.y += bb.y; a.z += bb.z; a.w += bb.w;
    *(float4*)(C + e) = a;
}

// ---------------------------------------------------------------------------
// k_attn (fused scores + cbar): per (b,h):
//   scores -> prefix softmax -> wbar[t,k] = (1/(t+1)) sum_{q<=t} E[q,k]/S[q,t]
//   cbar[t*16+b, h*512+d] = bf16( sum_k wbar[t,k] * v[k,b,h,d] )
// ---------------------------------------------------------------------------
__global__ __launch_bounds__(512) void k_attn(const float* __restrict__ qkv,
                                              ushort_t* __restrict__ cbar) {
    int bh = blockIdx.x;             // b*8 + h
    int b = bh >> 3, h = bh & 7;
    __shared__ float vs[T_LEN * HD];     // 48 KB
    __shared__ float ss[T_LEN][25];
    __shared__ float isv[T_LEN][25];
    __shared__ float wbs[TS * T_LEN];
    int tid = threadIdx.x, wave = tid >> 6, lane = tid & 63;
    // V -> LDS (overlaps with score dots below)
    for (int i4 = tid; i4 < T_LEN * HD / 4; i4 += 512) {
        int t = i4 >> 7, d4 = (i4 & 127) * 4;
        *(float4*)&vs[t * HD + d4] =
            *(const float4*)&qkv[(size_t)(t * BATCH + b) * QKV_N + 2 * E_DIM + h * HD + d4];
    }
    const float scale = 0.044194173824159216f;   // 1/sqrt(512)
    for (int p = wave; p < T_LEN * T_LEN; p += 8) {   // wave-per-dot, coalesced
        int qi = p / 24, ki = p - qi * 24;
        const float* qp = qkv + (size_t)(qi * BATCH + b) * QKV_N + h * HD + lane * 8;
        const float* kp = qkv + (size_t)(ki * BATCH + b) * QKV_N + E_DIM + h * HD + lane * 8;
        float4 a0 = *(const float4*)qp, a1 = *(const float4*)(qp + 4);
        float4 c0 = *(const float4*)kp, c1 = *(const float4*)(kp + 4);
        float s = a0.x * c0.x + a0.y * c0.y + a0.z * c0.z + a0.w * c0.w
                + a1.x * c1.x + a1.y * c1.y + a1.z * c1.z + a1.w * c1.w;
        #pragma unroll
        for (int off = 32; off > 0; off >>= 1) s += __shfl_xor(s, off);
        if (lane == 0) {
            s *= scale;
            if (ki <= qi) s += 1.f;      // tril_add (includes diagonal)
            ss[qi][ki] = s;
        }
    }
    __syncthreads();
    if (tid < T_LEN) {
        int q = tid;
        float M = -1e30f;
        for (int k = 0; k < T_LEN; ++k) M = fmaxf(M, ss[q][k]);
        float run = 0.f;
        for (int k = 0; k < T_LEN; ++k) {
            float e = __expf(ss[q][k] - M);
            ss[q][k] = e;
            run += e;
            isv[q][k] = 1.f / run;   // 1 / S[q, t=k]
        }
    }
    __syncthreads();
    for (int p = tid; p < TS * T_LEN; p += 512) {
        int t = p / 24, k = p - t * 24;
        float w = 0.f;
        if (k <= t) {
            float sum = 0.f;
            for (int q = 0; q <= t; ++q) sum += ss[q][k] * isv[q][t];
            w = sum / (float)(t + 1);
        }
        wbs[p] = w;
    }
    __syncthreads();
    int d = tid;                        // 512 threads == HD
    for (int t = 0; t < TS; ++t) {
        float a = 0.f;
        #pragma unroll
        for (int k = 0; k < T_LEN; ++k) a += wbs[t * 24 + k] * vs[k * HD + d];
        cbar[(size_t)(t * BATCH + b) * E_DIM + h * HD + d] = f2bf(a);
    }
}

// ---------------------------------------------------------------------------
// k_final: out[b, f, t+1, n] = relu( sum_g pooled[t*16+b, f*64+g]*Wfc[n,g] + bfc[n] )
// ---------------------------------------------------------------------------
__global__ void k_final(const float* __restrict__ pooled, const float* __restrict__ Wfc,
                        const float* __restrict__ bfc, float* __restrict__ out) {
    int tb = blockIdx.x;             // t*16 + b
    int t = tb >> 4, b = tb & 15;
    __shared__ float ps[E_DIM];      // 16 KB
    __shared__ float wf[64 * 65];    // padded
    __shared__ float bf[64];
    int tid = threadIdx.x;
    for (int i = tid; i < E_DIM; i += 256) ps[i] = pooled[(size_t)tb * E_DIM + i];
    for (int i = tid; i < 64 * 64; i += 256) wf[(i >> 6) * 65 + (i & 63)] = Wfc[i];
    if (tid < 64) bf[tid] = bfc[tid];
    __syncthreads();
    for (int p = tid; p < 4096; p += 256) {
        int f = p >> 6, n = p & 63;
        float acc = bf[n];
        #pragma unroll
        for (int g = 0; g < 64; ++g) acc += ps[f * 64 + g] * wf[n * 65 + g];
        out[(size_t)((b * 64 + f) * T_LEN + (t + 1)) * N_NODES + n] = fmaxf(acc, 0.f);
    }
}

// k_first: out[b,f,0,n] = x[b,f,0,n]   (65536 elems, 256 blocks)
__global__ void k_first(const float* __restrict__ x, float* __restrict__ out) {
    int idx = blockIdx.x * 256 + threadIdx.x;
    if (idx >= BATCH * F_DIM * N_NODES) return;
    int b = idx >> 12, f = (idx >> 6) & 63, n = idx & 63;
    size_t o = ((size_t)(b * 64 + f) * T_LEN) * 64 + n;
    out[o] = x[o];
}

extern "C" void kernel_launch(void* const* d_in, const int* in_sizes, int n_in,
                              void* d_out, int out_size, void* d_ws, size_t ws_size,
                              hipStream_t stream) {
    const float* x    = (const float*)d_in[0];
    const float* Wqkv = (const float*)d_in[1];
    const float* bqkv = (const float*)d_in[2];
    const float* Wo   = (const float*)d_in[3];
    const float* bo   = (const float*)d_in[4];
    const float* Wfc  = (const float*)d_in[5];
    const float* bfc  = (const float*)d_in[6];
    float* out = (float*)d_out;

    // ws layout (bytes): xt bf16 | qkv f32 | cbar bf16 | pooled f32 | pbuf f32
    char* wsb = (char*)d_ws;
    ushort_t* xt   = (ushort_t*)wsb;                                  //  3,145,728
    float*    qkv  = (float*)(wsb + 3145728);                         // 18,874,368
    ushort_t* cbar = (ushort_t*)(wsb + 3145728 + 18874368);           //  3,145,728
    float*  pooled = (float*)(wsb + 3145728 + 18874368 + 3145728);    //  6,291,456
    size_t base    = 3145728 + 18874368 + 3145728 + 6291456;
    float*  pbuf   = (float*)(wsb + base);

    const size_t pq = (size_t)MPAD * QKV_N * 4;    // QKV partial: 18.87 MB
    const size_t po = (size_t)MPAD * E_DIM * 4;    // Wo partial:   6.29 MB
    // K-splits for occupancy; kc % 128 == 0 required by the GEMM pipeline
    int S   = (ws_size >= base + 4 * pq) ? 4 : ((ws_size >= base + 2 * pq) ? 2 : 1);
    int Swo = (ws_size >= base + 8 * po) ? 8 : ((ws_size >= base + 4 * po) ? 4 : 1);

    hipLaunchKernelGGL(k_transpose, dim3(MB), dim3(256), 0, stream, x, xt);

    hipLaunchKernelGGL(k_gemm_mfma, dim3(QKV_N / 64, 1, S), dim3(256), 0, stream,
                       xt, Wqkv, pbuf, QKV_N, E_DIM, E_DIM / S);
    hipLaunchKernelGGL(k_reduce, dim3(MPAD * QKV_N / 4 / 256), dim3(256), 0, stream,
                       pbuf, bqkv, qkv, QKV_N, S);

    hipLaunchKernelGGL(k_attn, dim3(BATCH * N_HEADS), dim3(512), 0, stream, qkv, cbar);

    hipLaunchKernelGGL(k_gemm_mfma, dim3(E_DIM / 64, 1, Swo), dim3(256), 0, stream,
                       cbar, Wo, pbuf, E_DIM, E_DIM, E_DIM / Swo);
    hipLaunchKernelGGL(k_reduce, dim3(MPAD * E_DIM / 4 / 256), dim3(256), 0, stream,
                       pbuf, bo, pooled, E_DIM, Swo);

    hipLaunchKernelGGL(k_final, dim3(TS * BATCH), dim3(256), 0, stream, pooled, Wfc, bfc, out);
    hipLaunchKernelGGL(k_first, dim3((BATCH * F_DIM * N_NODES + 255) / 256), dim3(256), 0, stream, x, out);
}